// Round 5
// baseline (284.149 us; speedup 1.0000x reference)
//
#include <hip/hip_runtime.h>

// ---------------------------------------------------------------------------
// MHRPR chunk-attention pipeline for MI355X (gfx950), recomposed from
// HW-verified pieces only:
//   wcvt3_tiled : Wq,Wk,Wv f32 -> bf16 fragment-tiled
//   wcvt_row1   : Wo f32 -> bf16 row-major
//   xpose       : x q/k/v (B,D,T) f32 -> per-chunk fragment-tiled bf16
//   qkvproj2    : 1-wave blocks (mat,chunk,head); R2's verified project()
//                 loop (frags direct from global) + verified tile epilogue;
//                 writes Q,K as [t][hd], V as [hd][t] per (chunk,head)
//   attn3       : 1-wave blocks; R3's verified attention body; Q/K/V tiles
//                 copied global->LDS via inverse of verified stream-out
//   outgemm     : out = xo @ Wo^T + bo, * mask (128x128 MFMA GEMM, verified)
// Fallback: round-2 fused2 path if ws_size too small.
// ---------------------------------------------------------------------------

typedef __attribute__((ext_vector_type(8))) short short8;   // 8 bf16
typedef __attribute__((ext_vector_type(4))) float f32x4;
typedef __attribute__((ext_vector_type(2))) unsigned int uint2v;
typedef __attribute__((ext_vector_type(4))) unsigned short ushort4v;

#define DEV static __device__ __forceinline__

DEV unsigned short f2bf(float f) {                 // f32 -> bf16 RNE
  union { float f; unsigned int u; } x; x.f = f;
  unsigned int r = x.u + 0x7fffu + ((x.u >> 16) & 1u);
  return (unsigned short)(r >> 16);
}
DEV float bf2f(unsigned short h) {
  union { unsigned int u; float f; } x; x.u = ((unsigned int)h) << 16;
  return x.f;
}

DEV void gload16(char* lds, const void* g) {       // 16B global -> LDS direct
  __builtin_amdgcn_global_load_lds(
      (const __attribute__((address_space(1))) unsigned int*)g,
      (__attribute__((address_space(3))) unsigned int*)lds, 16, 0, 0);
}

constexpr int Bn = 4, Dm = 512, Tn = 8192, NC = 64;
constexpr int Gn = Tn / NC;            // 128
constexpr int BG = Bn * Gn;            // 512 chunks
constexpr int WSZ = Dm * Dm;           // 262144
constexpr size_t XTSZ = (size_t)Bn * Tn * Dm;   // 16777216 elems per tensor

// --- Wq,Wk,Wv -> tiled bf16: m*WSZ + (o>>6)*32768 + (d>>5)*2048 + (o&63)*32 + (d&31)
__global__ __launch_bounds__(256) void wcvt3_tiled(
    const float* __restrict__ wq, const float* __restrict__ wk,
    const float* __restrict__ wv, unsigned short* __restrict__ dst) {
  int i = blockIdx.x * 256 + threadIdx.x;          // 196608 float4 total
  int m = i >> 16, fi = i & 65535;
  int o = fi >> 7, d = (fi & 127) << 2;
  const float* src = (m == 0) ? wq : (m == 1) ? wk : wv;
  f32x4 v = *(const f32x4*)(src + o * Dm + d);
  ushort4v u;
  u[0] = f2bf(v[0]); u[1] = f2bf(v[1]); u[2] = f2bf(v[2]); u[3] = f2bf(v[3]);
  int doff = m * WSZ + ((o >> 6) << 15) + ((d >> 5) << 11) + ((o & 63) << 5) + (d & 31);
  *(ushort4v*)(dst + doff) = u;
}

// --- Wo -> row-major bf16 ---------------------------------------------------
__global__ __launch_bounds__(256) void wcvt_row1(
    const float* __restrict__ wo, unsigned short* __restrict__ dst) {
  int i = (blockIdx.x * 256 + threadIdx.x) * 4;    // 262144 elems
  f32x4 v = *(const f32x4*)(wo + i);
  ushort4v u;
  u[0] = f2bf(v[0]); u[1] = f2bf(v[1]); u[2] = f2bf(v[2]); u[3] = f2bf(v[3]);
  *(ushort4v*)(dst + i) = u;
}

// --- weights -> tiled bf16, 4 matrices (fallback path) ----------------------
__global__ __launch_bounds__(256) void wcvt_tiled(
    const float* __restrict__ wq, const float* __restrict__ wk,
    const float* __restrict__ wv, const float* __restrict__ wo,
    unsigned short* __restrict__ dst) {
  int i = blockIdx.x * 256 + threadIdx.x;
  int m = i >> 16, fi = i & 65535;
  int o = fi >> 7, d = (fi & 127) << 2;
  const float* src = (m == 0) ? wq : (m == 1) ? wk : (m == 2) ? wv : wo;
  f32x4 v = *(const f32x4*)(src + o * Dm + d);
  ushort4v u;
  u[0] = f2bf(v[0]); u[1] = f2bf(v[1]); u[2] = f2bf(v[2]); u[3] = f2bf(v[3]);
  int doff = m * WSZ + ((o >> 6) << 15) + ((d >> 5) << 11) + ((o & 63) << 5) + (d & 31);
  *(ushort4v*)(dst + doff) = u;
}

// --- x (B,D,T) f32 -> tiled bf16: c*32768 + (d>>5)*2048 + t*32 + (d&31) -----
__global__ __launch_bounds__(256) void xpose_kernel(
    const float* __restrict__ q, const float* __restrict__ k,
    const float* __restrict__ v, unsigned short* __restrict__ xt) {
  __shared__ unsigned short tile[64 * 65];
  const int tid = threadIdx.x, bid = blockIdx.x;
  const int tz = bid >> 12, rem = bid & 4095;
  const int cid = rem >> 3, dh = rem & 7;
  const int b = cid >> 7, t0 = (cid & 127) * 64, d0 = dh * 64;
  const float* xin = (tz == 0) ? q : (tz == 1) ? k : v;
  const int lane = tid & 63, drow = tid >> 6;
  const size_t base = (size_t)b * Dm * Tn + t0 + lane;
#pragma unroll
  for (int p = 0; p < 16; ++p) {
    int dr = drow + p * 4;
    float f = xin[base + (size_t)(d0 + dr) * Tn];
    tile[lane * 65 + dr] = f2bf(f);
  }
  __syncthreads();
  unsigned short* xb = xt + (size_t)tz * XTSZ + ((size_t)cid << 15) + (dh << 12);
  const int t = tid >> 2, dlo = (tid & 3) * 8;
#pragma unroll
  for (int h = 0; h < 2; ++h) {
    short8 s;
#pragma unroll
    for (int j = 0; j < 8; ++j) s[j] = (short)tile[t * 65 + h * 32 + dlo + j];
    *(short8*)(xb + h * 2048 + t * 32 + dlo) = s;
  }
}

// ---------------------------------------------------------------------------
// qkvproj2: one wave per (matrix, chunk, head). R2's verified project() loop,
// frags direct from global tiled layouts. Epilogue: verified tile + stream.
__global__ __launch_bounds__(64, 3)
void qkvproj2_kernel(const unsigned short* __restrict__ xt,
                     const unsigned short* __restrict__ wt3,
                     const float* __restrict__ bq, const float* __restrict__ bk,
                     const float* __restrict__ bv,
                     unsigned short* __restrict__ qkvf)
{
  __shared__ char ep[8192];
  const int lane = threadIdx.x;
  const int l15 = lane & 15, lg = lane >> 4;
  const int bid = blockIdx.x;
  const int mat = bid >> 12;           // 0=Q, 1=K, 2=V
  const int rem = bid & 4095;
  const int c = rem >> 3, h = rem & 7; // head h -> XCD h (W-slice L2-resident)
  const int aoff = l15 * 32 + lg * 8;
  const unsigned short* xb = xt + (size_t)mat * XTSZ + ((size_t)c << 15);
  const unsigned short* wb = wt3 + (size_t)mat * WSZ + ((size_t)h << 15);

  f32x4 acc[4][4];
  const f32x4 fzero = {0.f, 0.f, 0.f, 0.f};
#pragma unroll
  for (int mi = 0; mi < 4; ++mi)
#pragma unroll
    for (int ni = 0; ni < 4; ++ni) acc[mi][ni] = fzero;

#pragma unroll
  for (int kk = 0; kk < 16; ++kk) {
    short8 af[4], bf_[4];
#pragma unroll
    for (int mi = 0; mi < 4; ++mi)
      af[mi] = *(const short8*)(xb + kk * 2048 + mi * 512 + aoff);
#pragma unroll
    for (int ni = 0; ni < 4; ++ni)
      bf_[ni] = *(const short8*)(wb + kk * 2048 + ni * 512 + aoff);
#pragma unroll
    for (int ni = 0; ni < 4; ++ni)
#pragma unroll
      for (int mi = 0; mi < 4; ++mi)
        acc[mi][ni] = __builtin_amdgcn_mfma_f32_16x16x32_bf16(af[mi], bf_[ni],
                                                              acc[mi][ni], 0, 0, 0);
  }

  const float* bias = (mat == 0) ? bq : (mat == 1) ? bk : bv;

  if (mat < 2) {                    // Q,K: tile [t][hd], 128B rows swz ^((t&7)<<4)
#pragma unroll
    for (int ni = 0; ni < 4; ++ni) {
      float bi = bias[h * 64 + ni * 16 + l15];
      int hd = ni * 16 + l15;
#pragma unroll
      for (int mi = 0; mi < 4; ++mi)
#pragma unroll
        for (int rr = 0; rr < 4; ++rr) {
          int t = mi * 16 + lg * 4 + rr;
          int off = (t * 128 + hd * 2) ^ ((t & 7) << 4);
          *(unsigned short*)(ep + off) = f2bf(acc[mi][ni][rr] + bi);
        }
    }
  } else {                          // V: tile [hd][t]
#pragma unroll
    for (int ni = 0; ni < 4; ++ni) {
      float bi = bias[h * 64 + ni * 16 + l15];
      int hd = ni * 16 + l15;
#pragma unroll
      for (int mi = 0; mi < 4; ++mi) {
        unsigned int lo = (unsigned int)f2bf(acc[mi][ni][0] + bi) |
                          ((unsigned int)f2bf(acc[mi][ni][1] + bi) << 16);
        unsigned int hi = (unsigned int)f2bf(acc[mi][ni][2] + bi) |
                          ((unsigned int)f2bf(acc[mi][ni][3] + bi) << 16);
        uint2v pk; pk[0] = lo; pk[1] = hi;
        int tt = mi * 16 + lg * 4;
        int off = (hd * 128 + tt * 2) ^ ((hd & 7) << 4);
        *(uint2v*)(ep + off) = pk;
      }
    }
  }

  unsigned short* dst = qkvf + (size_t)mat * XTSZ + ((size_t)(c * 8 + h) << 12);
#pragma unroll
  for (int it = 0; it < 8; ++it) {
    int p = it * 64 + lane;
    int row = p >> 3, c16 = p & 7;
    short8 val = *(const short8*)(ep + ((row * 128 + c16 * 16) ^ ((row & 7) << 4)));
    *(short8*)(dst + row * 64 + c16 * 8) = val;
  }
}

// ---------------------------------------------------------------------------
// attn3: one wave per (chunk, head). R3's verified attention body; tiles
// copied from global via the inverse of the verified stream-out indexing.
__global__ __launch_bounds__(64, 3)
void attn3_kernel(const unsigned short* __restrict__ qkvf,
                  const float* __restrict__ masks,
                  const float* __restrict__ relk, const float* __restrict__ relv,
                  unsigned short* __restrict__ xo)
{
  __shared__ char ldsbuf[16384];
  char* regA = ldsbuf;            // Q tile, later V tile
  char* regB = ldsbuf + 8192;     // K tile, later P tile, later O tile
  const int lane = threadIdx.x;
  const int l15 = lane & 15, lg = lane >> 4;
  const int bid = blockIdx.x;
  const int c = bid >> 3, h = bid & 7;
  const int b = c >> 7, t0 = (c & 127) * 64;
  const size_t base = (size_t)(c * 8 + h) << 12;
  const unsigned short* qp = qkvf + base;
  const unsigned short* kp = qkvf + XTSZ + base;
  const unsigned short* vp = qkvf + 2 * XTSZ + base;

  float cmv = masks[(size_t)b * Tn + t0 + lane];
  unsigned long long nzb = __ballot(cmv != 0.0f);
  unsigned long long kpm = (nzb == 0ull) ? 0ull : __ballot(cmv == 0.0f);

  const f32x4 fzero = {0.f, 0.f, 0.f, 0.f};

  // ---- copy Q -> regA, K -> regB (swizzled; inverse of stream-out) ----
#pragma unroll
  for (int it = 0; it < 8; ++it) {
    int p = it * 64 + lane;
    int row = p >> 3, c16 = p & 7;
    int off = (row * 128 + c16 * 16) ^ ((row & 7) << 4);
    *(short8*)(regA + off) = *(const short8*)(qp + row * 64 + c16 * 8);
    *(short8*)(regB + off) = *(const short8*)(kp + row * 64 + c16 * 8);
  }

  // ---- S = Q K^T ----
  f32x4 sacc[4][4];
#pragma unroll
  for (int mi = 0; mi < 4; ++mi)
#pragma unroll
    for (int ni = 0; ni < 4; ++ni) sacc[mi][ni] = fzero;
#pragma unroll
  for (int kk = 0; kk < 2; ++kk) {
    short8 aq[4], bkf[4];
#pragma unroll
    for (int mi = 0; mi < 4; ++mi) {
      int t = mi * 16 + l15;
      int off = (t * 128 + (kk * 32 + lg * 8) * 2) ^ ((t & 7) << 4);
      aq[mi]  = *(const short8*)(regA + off);
      bkf[mi] = *(const short8*)(regB + off);
    }
#pragma unroll
    for (int ni = 0; ni < 4; ++ni)
#pragma unroll
      for (int mi = 0; mi < 4; ++mi)
        sacc[mi][ni] = __builtin_amdgcn_mfma_f32_16x16x32_bf16(aq[mi], bkf[ni], sacc[mi][ni], 0, 0, 0);
  }

  // ---- qrel[r] = sum_hd Q[qt=lane][hd] * rel_k[r][hd] ----
  float qr0 = 0, qr1 = 0, qr2 = 0, qr3 = 0, qr4 = 0;
#pragma unroll
  for (int g = 0; g < 8; ++g) {
    short8 q8 = *(const short8*)(regA + ((lane * 128 + g * 16) ^ ((lane & 7) << 4)));
#pragma unroll
    for (int j = 0; j < 8; ++j) {
      float qf = bf2f((unsigned short)q8[j]);
      qr0 += qf * relk[0 * 64 + g * 8 + j];
      qr1 += qf * relk[1 * 64 + g * 8 + j];
      qr2 += qf * relk[2 * 64 + g * 8 + j];
      qr3 += qf * relk[3 * 64 + g * 8 + j];
      qr4 += qf * relk[4 * 64 + g * 8 + j];
    }
  }

  // ---- copy V -> regA (Q dead after qrel) ----
#pragma unroll
  for (int it = 0; it < 8; ++it) {
    int p = it * 64 + lane;
    int row = p >> 3, c16 = p & 7;
    int off = (row * 128 + c16 * 16) ^ ((row & 7) << 4);
    *(short8*)(regA + off) = *(const short8*)(vp + row * 64 + c16 * 8);
  }

  // ---- softmax; P -> regB [qt][kt] (K dead) ----
  const float scale = 0.125f;
#pragma unroll
  for (int mi = 0; mi < 4; ++mi)
#pragma unroll
    for (int rr = 0; rr < 4; ++rr) {
      int qt = mi * 16 + lg * 4 + rr;
      float q0 = __shfl(qr0, qt), q1 = __shfl(qr1, qt), q2 = __shfl(qr2, qt),
            q3 = __shfl(qr3, qt), q4 = __shfl(qr4, qt);
      float sv[4];
#pragma unroll
      for (int ni = 0; ni < 4; ++ni) {
        int kt = ni * 16 + l15;
        int dd = kt - qt;
        float a2 = (dd <= -2) ? q0 : (dd == -1) ? q1 : (dd == 0) ? q2 : (dd == 1) ? q3 : q4;
        float s = (sacc[mi][ni][rr] + a2) * scale;
        if ((kpm >> kt) & 1ull) s = -1e30f;
        sv[ni] = s;
      }
      float m = fmaxf(fmaxf(sv[0], sv[1]), fmaxf(sv[2], sv[3]));
#pragma unroll
      for (int xm = 1; xm < 16; xm <<= 1) m = fmaxf(m, __shfl_xor(m, xm));
      float ssum = 0.f;
#pragma unroll
      for (int ni = 0; ni < 4; ++ni) { sv[ni] = __expf(sv[ni] - m); ssum += sv[ni]; }
#pragma unroll
      for (int xm = 1; xm < 16; xm <<= 1) ssum += __shfl_xor(ssum, xm);
      float inv = 1.0f / ssum;
#pragma unroll
      for (int ni = 0; ni < 4; ++ni) {
        int kt = ni * 16 + l15;
        int off = (qt * 128 + kt * 2) ^ ((qt & 7) << 4);
        *(unsigned short*)(regB + off) = f2bf(sv[ni] * inv);
      }
    }

  // ---- psum[qt=lane][r]: 5 class sums of P row ----
  float ps0 = 0, ps1 = 0, ps2 = 0, ps3 = 0, tot = 0;
#pragma unroll
  for (int g = 0; g < 8; ++g) {
    short8 p8 = *(const short8*)(regB + ((lane * 128 + g * 16) ^ ((lane & 7) << 4)));
#pragma unroll
    for (int j = 0; j < 8; ++j) {
      int kt = g * 8 + j;
      float p = bf2f((unsigned short)p8[j]);
      int dd = kt - lane;
      tot += p;
      ps0 += (dd <= -2) ? p : 0.f;
      ps1  = (dd == -1) ? p : ps1;
      ps2  = (dd ==  0) ? p : ps2;
      ps3  = (dd ==  1) ? p : ps3;
    }
  }
  float ps4 = tot - ps0 - ps1 - ps2 - ps3;

  // ---- O^T = V * P^T ----
  f32x4 oacc[4][4];
#pragma unroll
  for (int mi = 0; mi < 4; ++mi)
#pragma unroll
    for (int ni = 0; ni < 4; ++ni) oacc[mi][ni] = fzero;
#pragma unroll
  for (int kk = 0; kk < 2; ++kk) {
    short8 av[4], bp[4];
#pragma unroll
    for (int mi = 0; mi < 4; ++mi) {
      int row = mi * 16 + l15;
      int off = (row * 128 + (kk * 32 + lg * 8) * 2) ^ ((row & 7) << 4);
      av[mi] = *(const short8*)(regA + off);
      bp[mi] = *(const short8*)(regB + off);
    }
#pragma unroll
    for (int ni = 0; ni < 4; ++ni)
#pragma unroll
      for (int mi = 0; mi < 4; ++mi)
        oacc[mi][ni] = __builtin_amdgcn_mfma_f32_16x16x32_bf16(av[mi], bp[ni], oacc[mi][ni], 0, 0, 0);
  }

  // ---- O epilogue: +w2 (psum x rel_v); O -> regB [t][hd] ----
  float psh0[4], psh1[4], psh2[4], psh3[4], psh4[4];
#pragma unroll
  for (int ni = 0; ni < 4; ++ni) {
    int qt2 = ni * 16 + l15;
    psh0[ni] = __shfl(ps0, qt2); psh1[ni] = __shfl(ps1, qt2); psh2[ni] = __shfl(ps2, qt2);
    psh3[ni] = __shfl(ps3, qt2); psh4[ni] = __shfl(ps4, qt2);
  }
#pragma unroll
  for (int mi = 0; mi < 4; ++mi) {
    float rv_[4][5];
#pragma unroll
    for (int rr = 0; rr < 4; ++rr) {
      int hd = mi * 16 + lg * 4 + rr;
#pragma unroll
      for (int r = 0; r < 5; ++r) rv_[rr][r] = relv[r * 64 + hd];
    }
#pragma unroll
    for (int ni = 0; ni < 4; ++ni) {
      unsigned short u[4];
#pragma unroll
      for (int rr = 0; rr < 4; ++rr) {
        float w2 = psh0[ni] * rv_[rr][0] + psh1[ni] * rv_[rr][1] + psh2[ni] * rv_[rr][2]
                 + psh3[ni] * rv_[rr][3] + psh4[ni] * rv_[rr][4];
        u[rr] = f2bf(oacc[mi][ni][rr] + w2);
      }
      uint2v pk; pk[0] = u[0] | ((unsigned int)u[1] << 16);
      pk[1] = u[2] | ((unsigned int)u[3] << 16);
      int t = ni * 16 + l15;
      int off = (t * 128 + (mi * 16 + lg * 4) * 2) ^ ((t & 7) << 4);
      *(uint2v*)(regB + off) = pk;
    }
  }

  // ---- stream O tile to xo[t_g][512] ----
#pragma unroll
  for (int it = 0; it < 8; ++it) {
    int p = it * 64 + lane;
    int row = p >> 3, c16 = p & 7;
    short8 val = *(const short8*)(regB + ((row * 128 + c16 * 16) ^ ((row & 7) << 4)));
    *(short8*)(xo + (size_t)(c * 64 + row) * Dm + h * 64 + c16 * 8) = val;
  }
}

// ---------------------------------------------------------------------------
// outgemm: out[b][o][t] = (sum_d xo[t_g][d] * Wo[o][d] + bo[o]) * mask[b][t]
__global__ __launch_bounds__(256, 2)
void outgemm_kernel(const unsigned short* __restrict__ xo,
                    const unsigned short* __restrict__ wo,
                    const float* __restrict__ masks, const float* __restrict__ bo,
                    float* __restrict__ out)
{
  __shared__ char lA[16384], lB[16384];
  const int tid = threadIdx.x;
  const int lane = tid & 63, w = tid >> 6;
  const int wm = w >> 1, wn = w & 1;
  const int l15 = lane & 15, lg = lane >> 4;
  const int bidx = blockIdx.x;
  const int n0 = (bidx & 3) * 128, m0 = (bidx >> 2) * 128;

  f32x4 acc[4][4];
  const f32x4 fzero = {0.f, 0.f, 0.f, 0.f};
#pragma unroll
  for (int mi = 0; mi < 4; ++mi)
#pragma unroll
    for (int ni = 0; ni < 4; ++ni) acc[mi][ni] = fzero;

  for (int k0 = 0; k0 < 512; k0 += 64) {
#pragma unroll
    for (int it = 0; it < 4; ++it) {
      int slot = it * 256 + w * 64 + lane;
      int row = slot >> 3, c16 = slot & 7;
      int gcol = k0 + ((c16 ^ (row & 7)) * 8);
      gload16(lA + it * 4096 + w * 1024, xo + (size_t)(m0 + row) * Dm + gcol);
      gload16(lB + it * 4096 + w * 1024, wo + (size_t)(n0 + row) * Dm + gcol);
    }
    __syncthreads();
#pragma unroll
    for (int kk = 0; kk < 2; ++kk) {
      short8 af[4], bf_[4];
#pragma unroll
      for (int mi = 0; mi < 4; ++mi) {
        int m = wm * 64 + mi * 16 + l15;
        af[mi] = *(const short8*)(lA + ((m * 128 + (kk * 32 + lg * 8) * 2) ^ ((m & 7) << 4)));
      }
#pragma unroll
      for (int ni = 0; ni < 4; ++ni) {
        int n = wn * 64 + ni * 16 + l15;
        bf_[ni] = *(const short8*)(lB + ((n * 128 + (kk * 32 + lg * 8) * 2) ^ ((n & 7) << 4)));
      }
#pragma unroll
      for (int ni = 0; ni < 4; ++ni)
#pragma unroll
        for (int mi = 0; mi < 4; ++mi)
          acc[mi][ni] = __builtin_amdgcn_mfma_f32_16x16x32_bf16(af[mi], bf_[ni], acc[mi][ni], 0, 0, 0);
    }
    __syncthreads();
  }

#pragma unroll
  for (int mi = 0; mi < 4; ++mi) {
    int tg = m0 + wm * 64 + mi * 16 + lg * 4;
    int b = tg >> 13, t = tg & (Tn - 1);
    f32x4 mv = *(const f32x4*)(masks + (size_t)b * Tn + t);
#pragma unroll
    for (int ni = 0; ni < 4; ++ni) {
      int o = n0 + wn * 64 + ni * 16 + l15;
      float bia = bo[o];
      f32x4 r;
#pragma unroll
      for (int rr = 0; rr < 4; ++rr) r[rr] = (acc[mi][ni][rr] + bia) * mv[rr];
      *(f32x4*)(out + ((size_t)b * Dm + o) * Tn + t) = r;
    }
  }
}

// ===========================================================================
// Fallback: round-2 fused2 path (ws too small for split pipeline)
// ===========================================================================
__global__ __launch_bounds__(512, 2)
void fused2_kernel(const unsigned short* __restrict__ xt,
                   const float* __restrict__ masks,
                   const unsigned short* __restrict__ wbf,
                   const float* __restrict__ bq, const float* __restrict__ bk,
                   const float* __restrict__ bv, const float* __restrict__ bo,
                   const float* __restrict__ relk, const float* __restrict__ relv,
                   float* __restrict__ out)
{
  extern __shared__ char lds[];
  const int tid  = threadIdx.x;
  const int lane = tid & 63;
  const int w    = tid >> 6;
  const int l15  = lane & 15;
  const int lg   = lane >> 4;
  const int c    = blockIdx.x;
  const int b    = c >> 7;
  const int t0   = (c & (Gn - 1)) * NC;

  char* regA = lds + w * 16384;
  char* regB = regA + 8192;

  float cmv = masks[(size_t)b * Tn + t0 + lane];
  unsigned long long nzb = __ballot(cmv != 0.0f);
  unsigned long long kpm = (nzb == 0ull) ? 0ull : __ballot(cmv == 0.0f);

  const f32x4 fzero = {0.f, 0.f, 0.f, 0.f};
  const int aoff = l15 * 32 + lg * 8;
  const unsigned short* xq = xt + ((size_t)c << 15);
  const unsigned short* xk = xq + XTSZ;
  const unsigned short* xv = xq + 2 * XTSZ;

  auto project = [&](const unsigned short* __restrict__ xb,
                     const unsigned short* __restrict__ wb, f32x4 (&acc)[4][4]) {
#pragma unroll
    for (int mi = 0; mi < 4; ++mi)
#pragma unroll
      for (int ni = 0; ni < 4; ++ni) acc[mi][ni] = fzero;
#pragma unroll
    for (int kk = 0; kk < 16; ++kk) {
      short8 af[4], bf_[4];
#pragma unroll
      for (int mi = 0; mi < 4; ++mi)
        af[mi] = *(const short8*)(xb + kk * 2048 + mi * 512 + aoff);
#pragma unroll
      for (int ni = 0; ni < 4; ++ni)
        bf_[ni] = *(const short8*)(wb + kk * 2048 + ni * 512 + aoff);
#pragma unroll
      for (int ni = 0; ni < 4; ++ni)
#pragma unroll
        for (int mi = 0; mi < 4; ++mi)
          acc[mi][ni] = __builtin_amdgcn_mfma_f32_16x16x32_bf16(af[mi], bf_[ni],
                                                                acc[mi][ni], 0, 0, 0);
    }
  };

  f32x4 acc[4][4];

  project(xq, wbf + 0 * WSZ + w * 32768, acc);
#pragma unroll
  for (int ni = 0; ni < 4; ++ni) {
    float bia = bq[64 * w + ni * 16 + l15];
    int hd = ni * 16 + l15;
#pragma unroll
    for (int mi = 0; mi < 4; ++mi)
#pragma unroll
      for (int rr = 0; rr < 4; ++rr) {
        int t = mi * 16 + lg * 4 + rr;
        int off = (t * 128 + hd * 2) ^ ((t & 7) << 4);
        *(unsigned short*)(regA + off) = f2bf(acc[mi][ni][rr] + bia);
      }
  }

  project(xk, wbf + 1 * WSZ + w * 32768, acc);
#pragma unroll
  for (int ni = 0; ni < 4; ++ni) {
    float bia = bk[64 * w + ni * 16 + l15];
    int hd = ni * 16 + l15;
#pragma unroll
    for (int mi = 0; mi < 4; ++mi)
#pragma unroll
      for (int rr = 0; rr < 4; ++rr) {
        int t = mi * 16 + lg * 4 + rr;
        int off = (t * 128 + hd * 2) ^ ((t & 7) << 4);
        *(unsigned short*)(regB + off) = f2bf(acc[mi][ni][rr] + bia);
      }
  }

  f32x4 sacc[4][4];
#pragma unroll
  for (int mi = 0; mi < 4; ++mi)
#pragma unroll
    for (int ni = 0; ni < 4; ++ni) sacc[mi][ni] = fzero;
#pragma unroll
  for (int kk = 0; kk < 2; ++kk) {
    short8 aq[4], bkf[4];
#pragma unroll
    for (int mi = 0; mi < 4; ++mi) {
      int t = mi * 16 + l15;
      int off = (t * 128 + (kk * 32 + lg * 8) * 2) ^ ((t & 7) << 4);
      aq[mi]  = *(const short8*)(regA + off);
      bkf[mi] = *(const short8*)(regB + off);
    }
#pragma unroll
    for (int ni = 0; ni < 4; ++ni)
#pragma unroll
      for (int mi = 0; mi < 4; ++mi)
        sacc[mi][ni] = __builtin_amdgcn_mfma_f32_16x16x32_bf16(aq[mi], bkf[ni],
                                                               sacc[mi][ni], 0, 0, 0);
  }

  float qr0 = 0, qr1 = 0, qr2 = 0, qr3 = 0, qr4 = 0;
#pragma unroll
  for (int g = 0; g < 8; ++g) {
    short8 q8 = *(const short8*)(regA + ((lane * 128 + g * 16) ^ ((lane & 7) << 4)));
#pragma unroll
    for (int j = 0; j < 8; ++j) {
      float qf = bf2f((unsigned short)q8[j]);
      qr0 += qf * relk[0 * 64 + g * 8 + j];
      qr1 += qf * relk[1 * 64 + g * 8 + j];
      qr2 += qf * relk[2 * 64 + g * 8 + j];
      qr3 += qf * relk[3 * 64 + g * 8 + j];
      qr4 += qf * relk[4 * 64 + g * 8 + j];
    }
  }

  const float scale = 0.125f;
#pragma unroll
  for (int mi = 0; mi < 4; ++mi)
#pragma unroll
    for (int rr = 0; rr < 4; ++rr) {
      int qt = mi * 16 + lg * 4 + rr;
      float q0 = __shfl(qr0, qt), q1 = __shfl(qr1, qt), q2 = __shfl(qr2, qt),
            q3 = __shfl(qr3, qt), q4 = __shfl(qr4, qt);
      float sv[4];
#pragma unroll
      for (int ni = 0; ni < 4; ++ni) {
        int kt = ni * 16 + l15;
        int dd = kt - qt;
        float a2 = (dd <= -2) ? q0 : (dd == -1) ? q1 : (dd == 0) ? q2 : (dd == 1) ? q3 : q4;
        float s = (sacc[mi][ni][rr] + a2) * scale;
        if ((kpm >> kt) & 1ull) s = -1e30f;
        sv[ni] = s;
      }
      float m = fmaxf(fmaxf(sv[0], sv[1]), fmaxf(sv[2], sv[3]));
#pragma unroll
      for (int xm = 1; xm < 16; xm <<= 1) m = fmaxf(m, __shfl_xor(m, xm));
      float ssum = 0.f;
#pragma unroll
      for (int ni = 0; ni < 4; ++ni) { sv[ni] = __expf(sv[ni] - m); ssum += sv[ni]; }
#pragma unroll
      for (int xm = 1; xm < 16; xm <<= 1) ssum += __shfl_xor(ssum, xm);
      float inv = 1.0f / ssum;
#pragma unroll
      for (int ni = 0; ni < 4; ++ni) {
        int kt = ni * 16 + l15;
        int off = (qt * 128 + kt * 2) ^ ((qt & 7) << 4);
        *(unsigned short*)(regB + off) = f2bf(sv[ni] * inv);
      }
    }

  float ps0 = 0, ps1 = 0, ps2 = 0, ps3 = 0, tot = 0;
#pragma unroll
  for (int g = 0; g < 8; ++g) {
    short8 p8 = *(const short8*)(regB + ((lane * 128 + g * 16) ^ ((lane & 7) << 4)));
#pragma unroll
    for (int j = 0; j < 8; ++j) {
      int kt = g * 8 + j;
      float p = bf2f((unsigned short)p8[j]);
      int dd = kt - lane;
      tot += p;
      ps0 += (dd <= -2) ? p : 0.f;
      ps1  = (dd == -1) ? p : ps1;
      ps2  = (dd ==  0) ? p : ps2;
      ps3  = (dd ==  1) ? p : ps3;
    }
  }
  float ps4 = tot - ps0 - ps1 - ps2 - ps3;

  project(xv, wbf + 2 * WSZ + w * 32768, acc);
#pragma unroll
  for (int ni = 0; ni < 4; ++ni) {
    float bia = bv[64 * w + ni * 16 + l15];
    int hd = ni * 16 + l15;
#pragma unroll
    for (int mi = 0; mi < 4; ++mi) {
      unsigned int lo = (unsigned int)f2bf(acc[mi][ni][0] + bia) |
                        ((unsigned int)f2bf(acc[mi][ni][1] + bia) << 16);
      unsigned int hi = (unsigned int)f2bf(acc[mi][ni][2] + bia) |
                        ((unsigned int)f2bf(acc[mi][ni][3] + bia) << 16);
      uint2v pk; pk[0] = lo; pk[1] = hi;
      int off = (hd * 128 + (mi * 16 + lg * 4) * 2) ^ ((hd & 7) << 4);
      *(uint2v*)(regA + off) = pk;
    }
  }

  f32x4 oacc[4][4];
#pragma unroll
  for (int mi = 0; mi < 4; ++mi)
#pragma unroll
    for (int ni = 0; ni < 4; ++ni) oacc[mi][ni] = fzero;
#pragma unroll
  for (int kk = 0; kk < 2; ++kk) {
    short8 av[4], bp[4];
#pragma unroll
    for (int mi = 0; mi < 4; ++mi) {
      int row = mi * 16 + l15;
      int off = (row * 128 + (kk * 32 + lg * 8) * 2) ^ ((row & 7) << 4);
      av[mi] = *(const short8*)(regA + off);
      bp[mi] = *(const short8*)(regB + off);
    }
#pragma unroll
    for (int ni = 0; ni < 4; ++ni)
#pragma unroll
      for (int mi = 0; mi < 4; ++mi)
        oacc[mi][ni] = __builtin_amdgcn_mfma_f32_16x16x32_bf16(av[mi], bp[ni],
                                                               oacc[mi][ni], 0, 0, 0);
  }

  float psh0[4], psh1[4], psh2[4], psh3[4], psh4[4];
#pragma unroll
  for (int ni = 0; ni < 4; ++ni) {
    int qt2 = ni * 16 + l15;
    psh0[ni] = __shfl(ps0, qt2); psh1[ni] = __shfl(ps1, qt2); psh2[ni] = __shfl(ps2, qt2);
    psh3[ni] = __shfl(ps3, qt2); psh4[ni] = __shfl(ps4, qt2);
  }
  uint2v xop[4][4];
#pragma unroll
  for (int mi = 0; mi < 4; ++mi) {
    float rv_[4][5];
#pragma unroll
    for (int rr = 0; rr < 4; ++rr) {
      int hd = mi * 16 + lg * 4 + rr;
#pragma unroll
      for (int r = 0; r < 5; ++r) rv_[rr][r] = relv[r * 64 + hd];
    }
#pragma unroll
    for (int ni = 0; ni < 4; ++ni) {
      unsigned short u[4];
#pragma unroll
      for (int rr = 0; rr < 4; ++rr) {
        float w2 = psh0[ni] * rv_[rr][0] + psh1[ni] * rv_[rr][1] + psh2[ni] * rv_[rr][2]
                 + psh3[ni] * rv_[rr][3] + psh4[ni] * rv_[rr][4];
        u[rr] = f2bf(oacc[mi][ni][rr] + w2);
      }
      uint2v pk; pk[0] = u[0] | ((unsigned int)u[1] << 16);
      pk[1] = u[2] | ((unsigned int)u[3] << 16);
      xop[mi][ni] = pk;
    }
  }

  __syncthreads();
  char* xobuf = lds;
#pragma unroll
  for (int ni = 0; ni < 4; ++ni) {
    int t = ni * 16 + l15;
#pragma unroll
    for (int mi = 0; mi < 4; ++mi) {
      int d = 64 * w + mi * 16 + lg * 4;
      int off = (t * 1024 + d * 2) ^ ((t & 15) << 4);
      *(uint2v*)(xobuf + off) = xop[mi][ni];
    }
  }
  __syncthreads();

  f32x4 cacc[4][4];
#pragma unroll
  for (int mi = 0; mi < 4; ++mi)
#pragma unroll
    for (int ni = 0; ni < 4; ++ni) cacc[mi][ni] = fzero;
  const unsigned short* wob = wbf + 3 * WSZ + w * 32768;
#pragma unroll
  for (int kk = 0; kk < 16; ++kk) {
    short8 ax[4], bw[4];
#pragma unroll
    for (int mi = 0; mi < 4; ++mi) {
      int t = mi * 16 + l15;
      int off = (t * 1024 + (kk * 32 + lg * 8) * 2) ^ ((t & 15) << 4);
      ax[mi] = *(const short8*)(xobuf + off);
    }
#pragma unroll
    for (int ni = 0; ni < 4; ++ni)
      bw[ni] = *(const short8*)(wob + kk * 2048 + ni * 512 + l15 * 32 + lg * 8);
#pragma unroll
    for (int ni = 0; ni < 4; ++ni)
#pragma unroll
      for (int mi = 0; mi < 4; ++mi)
        cacc[mi][ni] = __builtin_amdgcn_mfma_f32_16x16x32_bf16(ax[mi], bw[ni],
                                                               cacc[mi][ni], 0, 0, 0);
  }
#pragma unroll
  for (int mi = 0; mi < 4; ++mi) {
    int tl = mi * 16 + lg * 4;
    f32x4 mv = *(const f32x4*)(masks + (size_t)b * Tn + t0 + tl);
#pragma unroll
    for (int ni = 0; ni < 4; ++ni) {
      int o = 64 * w + ni * 16 + l15;
      float bia = bo[o];
      f32x4 r;
#pragma unroll
      for (int rr = 0; rr < 4; ++rr) r[rr] = (cacc[mi][ni][rr] + bia) * mv[rr];
      *(f32x4*)(out + ((size_t)b * Dm + o) * Tn + t0 + tl) = r;
    }
  }
}

// ---------------------------------------------------------------------------
extern "C" void kernel_launch(void* const* d_in, const int* in_sizes, int n_in,
                              void* d_out, int out_size, void* d_ws, size_t ws_size,
                              hipStream_t stream) {
  (void)in_sizes; (void)n_in; (void)out_size;
  const float* q  = (const float*)d_in[0];
  const float* k  = (const float*)d_in[1];
  const float* v  = (const float*)d_in[2];
  const float* ms = (const float*)d_in[3];
  const float* Wq = (const float*)d_in[4];
  const float* bq = (const float*)d_in[5];
  const float* Wk = (const float*)d_in[6];
  const float* bk = (const float*)d_in[7];
  const float* Wv = (const float*)d_in[8];
  const float* bv = (const float*)d_in[9];
  const float* Wo = (const float*)d_in[10];
  const float* bo = (const float*)d_in[11];
  const float* rk = (const float*)d_in[12];
  const float* rv = (const float*)d_in[13];
  float* out = (float*)d_out;

  const size_t needNew = ((size_t)4 * WSZ + 6 * XTSZ) * 2;   // ~203 MB

  if (ws_size >= needNew) {
    unsigned short* wt3   = (unsigned short*)d_ws;     // tiled Wq|Wk|Wv
    unsigned short* worow = wt3 + 3 * WSZ;             // row-major Wo
    unsigned short* xt    = worow + WSZ;               // 3 x tiled inputs
    unsigned short* qkvf  = xt + 3 * XTSZ;             // Qf|Kf|Vf
    unsigned short* xo    = xt;                        // alias (xt dead)
    wcvt3_tiled<<<dim3(768), dim3(256), 0, stream>>>(Wq, Wk, Wv, wt3);
    wcvt_row1<<<dim3(256), dim3(256), 0, stream>>>(Wo, worow);
    xpose_kernel<<<dim3(12288), dim3(256), 0, stream>>>(q, k, v, xt);
    qkvproj2_kernel<<<dim3(12288), dim3(64), 0, stream>>>(xt, wt3, bq, bk, bv, qkvf);
    attn3_kernel<<<dim3(4096), dim3(64), 0, stream>>>(qkvf, ms, rk, rv, xo);
    outgemm_kernel<<<dim3(1024), dim3(256), 0, stream>>>(xo, worow, ms, bo, out);
  } else {
    unsigned short* wbf = (unsigned short*)d_ws;
    unsigned short* xt = wbf + 4 * WSZ;
    wcvt_tiled<<<dim3(1024), dim3(256), 0, stream>>>(Wq, Wk, Wv, Wo, wbf);
    xpose_kernel<<<dim3(12288), dim3(256), 0, stream>>>(q, k, v, xt);
    hipFuncSetAttribute((const void*)fused2_kernel,
                        hipFuncAttributeMaxDynamicSharedMemorySize, 131072);
    fused2_kernel<<<dim3(BG), dim3(512), 131072, stream>>>(xt, ms, wbf,
                                                           bq, bk, bv, bo, rk, rv, out);
  }
}

// Round 6
// 199.654 us; speedup vs baseline: 1.4232x; 1.4232x over previous
//
#include <hip/hip_runtime.h>

// ---------------------------------------------------------------------------
// MHRPR chunk-attention pipeline for MI355X (gfx950):
//   wcvt3_tiled : Wq,Wk,Wv f32 -> bf16 fragment-tiled
//   wcvt_row1   : Wo f32 -> bf16 row-major
//   qkvproj3    : block=(mat,chunk), 8 waves=8 heads SHARING one x tile;
//                 fused x transpose (f32 global -> bf16 LDS) + projection;
//                 writes Q,K as [t][hd], V as [hd][t] per (chunk,head)
//   attn3       : 1-wave blocks; verified attention body (R5)
//   outgemm     : out = xo @ Wo^T + bo, * mask (128x128 MFMA GEMM, verified)
// Fallback: round-2 fused2 path if ws_size too small.
// ---------------------------------------------------------------------------

typedef __attribute__((ext_vector_type(8))) short short8;   // 8 bf16
typedef __attribute__((ext_vector_type(4))) float f32x4;
typedef __attribute__((ext_vector_type(2))) unsigned int uint2v;
typedef __attribute__((ext_vector_type(4))) unsigned short ushort4v;

#define DEV static __device__ __forceinline__

DEV unsigned short f2bf(float f) {                 // f32 -> bf16 RNE
  union { float f; unsigned int u; } x; x.f = f;
  unsigned int r = x.u + 0x7fffu + ((x.u >> 16) & 1u);
  return (unsigned short)(r >> 16);
}
DEV float bf2f(unsigned short h) {
  union { unsigned int u; float f; } x; x.u = ((unsigned int)h) << 16;
  return x.f;
}

DEV void gload16(char* lds, const void* g) {       // 16B global -> LDS direct
  __builtin_amdgcn_global_load_lds(
      (const __attribute__((address_space(1))) unsigned int*)g,
      (__attribute__((address_space(3))) unsigned int*)lds, 16, 0, 0);
}

constexpr int Bn = 4, Dm = 512, Tn = 8192, NC = 64;
constexpr int Gn = Tn / NC;            // 128
constexpr int BG = Bn * Gn;            // 512 chunks
constexpr int WSZ = Dm * Dm;           // 262144
constexpr size_t XTSZ = (size_t)Bn * Tn * Dm;   // 16777216 elems per tensor

// --- Wq,Wk,Wv -> tiled bf16: m*WSZ + (o>>6)*32768 + (d>>5)*2048 + (o&63)*32 + (d&31)
__global__ __launch_bounds__(256) void wcvt3_tiled(
    const float* __restrict__ wq, const float* __restrict__ wk,
    const float* __restrict__ wv, unsigned short* __restrict__ dst) {
  int i = blockIdx.x * 256 + threadIdx.x;          // 196608 float4 total
  int m = i >> 16, fi = i & 65535;
  int o = fi >> 7, d = (fi & 127) << 2;
  const float* src = (m == 0) ? wq : (m == 1) ? wk : wv;
  f32x4 v = *(const f32x4*)(src + o * Dm + d);
  ushort4v u;
  u[0] = f2bf(v[0]); u[1] = f2bf(v[1]); u[2] = f2bf(v[2]); u[3] = f2bf(v[3]);
  int doff = m * WSZ + ((o >> 6) << 15) + ((d >> 5) << 11) + ((o & 63) << 5) + (d & 31);
  *(ushort4v*)(dst + doff) = u;
}

// --- Wo -> row-major bf16 ---------------------------------------------------
__global__ __launch_bounds__(256) void wcvt_row1(
    const float* __restrict__ wo, unsigned short* __restrict__ dst) {
  int i = (blockIdx.x * 256 + threadIdx.x) * 4;    // 262144 elems
  f32x4 v = *(const f32x4*)(wo + i);
  ushort4v u;
  u[0] = f2bf(v[0]); u[1] = f2bf(v[1]); u[2] = f2bf(v[2]); u[3] = f2bf(v[3]);
  *(ushort4v*)(dst + i) = u;
}

// --- weights -> tiled bf16, 4 matrices (fallback path) ----------------------
__global__ __launch_bounds__(256) void wcvt_tiled(
    const float* __restrict__ wq, const float* __restrict__ wk,
    const float* __restrict__ wv, const float* __restrict__ wo,
    unsigned short* __restrict__ dst) {
  int i = blockIdx.x * 256 + threadIdx.x;
  int m = i >> 16, fi = i & 65535;
  int o = fi >> 7, d = (fi & 127) << 2;
  const float* src = (m == 0) ? wq : (m == 1) ? wk : (m == 2) ? wv : wo;
  f32x4 v = *(const f32x4*)(src + o * Dm + d);
  ushort4v u;
  u[0] = f2bf(v[0]); u[1] = f2bf(v[1]); u[2] = f2bf(v[2]); u[3] = f2bf(v[3]);
  int doff = m * WSZ + ((o >> 6) << 15) + ((d >> 5) << 11) + ((o & 63) << 5) + (d & 31);
  *(ushort4v*)(dst + doff) = u;
}

// --- x (B,D,T) f32 -> tiled bf16 (fallback path only) -----------------------
__global__ __launch_bounds__(256) void xpose_kernel(
    const float* __restrict__ q, const float* __restrict__ k,
    const float* __restrict__ v, unsigned short* __restrict__ xt) {
  __shared__ unsigned short tile[64 * 65];
  const int tid = threadIdx.x, bid = blockIdx.x;
  const int tz = bid >> 12, rem = bid & 4095;
  const int cid = rem >> 3, dh = rem & 7;
  const int b = cid >> 7, t0 = (cid & 127) * 64, d0 = dh * 64;
  const float* xin = (tz == 0) ? q : (tz == 1) ? k : v;
  const int lane = tid & 63, drow = tid >> 6;
  const size_t base = (size_t)b * Dm * Tn + t0 + lane;
#pragma unroll
  for (int p = 0; p < 16; ++p) {
    int dr = drow + p * 4;
    float f = xin[base + (size_t)(d0 + dr) * Tn];
    tile[lane * 65 + dr] = f2bf(f);
  }
  __syncthreads();
  unsigned short* xb = xt + (size_t)tz * XTSZ + ((size_t)cid << 15) + (dh << 12);
  const int t = tid >> 2, dlo = (tid & 3) * 8;
#pragma unroll
  for (int h = 0; h < 2; ++h) {
    short8 s;
#pragma unroll
    for (int j = 0; j < 8; ++j) s[j] = (short)tile[t * 65 + h * 32 + dlo + j];
    *(short8*)(xb + h * 2048 + t * 32 + dlo) = s;
  }
}

// ---------------------------------------------------------------------------
// qkvproj3: block = (matrix, chunk); 8 waves = 8 heads share one x tile.
// Fused transpose: x f32 (B,D,T) -> LDS St[t][d] bf16 (1KB rows, ^((t&15)<<4)).
__global__ __launch_bounds__(512, 2)
void qkvproj3_kernel(const float* __restrict__ qx, const float* __restrict__ kx,
                     const float* __restrict__ vx,
                     const unsigned short* __restrict__ wt3,
                     const float* __restrict__ bq, const float* __restrict__ bk,
                     const float* __restrict__ bv,
                     unsigned short* __restrict__ qkvf)
{
  __shared__ char st[65536];        // x tile; reused as 8x8KB epilogue scratch
  const int tid = threadIdx.x;
  const int lane = tid & 63, w = tid >> 6;
  const int l15 = lane & 15, lg = lane >> 4;
  const int bid = blockIdx.x;
  const int mat = bid >> 9;         // 0=Q, 1=K, 2=V  (grid 1536)
  const int c = bid & 511;
  const int b = c >> 7, t0 = (c & 127) * 64;
  const float* xin = (mat == 0) ? qx : (mat == 1) ? kx : vx;

  // ---- stage: St[t=lane][d] = bf16(x[b][d][t0+lane]) ----
  const size_t xbase = (size_t)b * Dm * Tn + t0 + lane;
#pragma unroll
  for (int s = 0; s < 8; ++s) {
    int d0 = s * 64 + w * 8;
    short8 pk;
#pragma unroll
    for (int j = 0; j < 8; ++j)
      pk[j] = (short)f2bf(xin[xbase + (size_t)(d0 + j) * Tn]);
    int off = (lane * 1024 + d0 * 2) ^ ((lane & 15) << 4);
    *(short8*)(st + off) = pk;
  }
  __syncthreads();

  // ---- projection: wave w = head h; A from LDS, B (weights) from global ----
  const int h = w;
  const unsigned short* wb = wt3 + (size_t)mat * WSZ + ((size_t)h << 15);
  const int aoff = l15 * 32 + lg * 8;

  f32x4 acc[4][4];
  const f32x4 fzero = {0.f, 0.f, 0.f, 0.f};
#pragma unroll
  for (int mi = 0; mi < 4; ++mi)
#pragma unroll
    for (int ni = 0; ni < 4; ++ni) acc[mi][ni] = fzero;

#pragma unroll
  for (int kk = 0; kk < 16; ++kk) {
    short8 af[4], bf_[4];
#pragma unroll
    for (int mi = 0; mi < 4; ++mi) {
      int t = mi * 16 + l15;
      int off = (t * 1024 + (kk * 32 + lg * 8) * 2) ^ ((t & 15) << 4);
      af[mi] = *(const short8*)(st + off);
    }
#pragma unroll
    for (int ni = 0; ni < 4; ++ni)
      bf_[ni] = *(const short8*)(wb + kk * 2048 + ni * 512 + aoff);
#pragma unroll
    for (int ni = 0; ni < 4; ++ni)
#pragma unroll
      for (int mi = 0; mi < 4; ++mi)
        acc[mi][ni] = __builtin_amdgcn_mfma_f32_16x16x32_bf16(af[mi], bf_[ni],
                                                              acc[mi][ni], 0, 0, 0);
  }
  __syncthreads();                  // all waves done reading the x tile

  // ---- epilogue (R5-verified): bias + per-wave LDS tile + coalesced stream
  char* ep = st + w * 8192;
  const float* bias = (mat == 0) ? bq : (mat == 1) ? bk : bv;

  if (mat < 2) {                    // Q,K: tile [t][hd], 128B rows swz ^((t&7)<<4)
#pragma unroll
    for (int ni = 0; ni < 4; ++ni) {
      float bi = bias[h * 64 + ni * 16 + l15];
      int hd = ni * 16 + l15;
#pragma unroll
      for (int mi = 0; mi < 4; ++mi)
#pragma unroll
        for (int rr = 0; rr < 4; ++rr) {
          int t = mi * 16 + lg * 4 + rr;
          int off = (t * 128 + hd * 2) ^ ((t & 7) << 4);
          *(unsigned short*)(ep + off) = f2bf(acc[mi][ni][rr] + bi);
        }
    }
  } else {                          // V: tile [hd][t]
#pragma unroll
    for (int ni = 0; ni < 4; ++ni) {
      float bi = bias[h * 64 + ni * 16 + l15];
      int hd = ni * 16 + l15;
#pragma unroll
      for (int mi = 0; mi < 4; ++mi) {
        unsigned int lo = (unsigned int)f2bf(acc[mi][ni][0] + bi) |
                          ((unsigned int)f2bf(acc[mi][ni][1] + bi) << 16);
        unsigned int hi = (unsigned int)f2bf(acc[mi][ni][2] + bi) |
                          ((unsigned int)f2bf(acc[mi][ni][3] + bi) << 16);
        uint2v pk; pk[0] = lo; pk[1] = hi;
        int tt = mi * 16 + lg * 4;
        int off = (hd * 128 + tt * 2) ^ ((hd & 7) << 4);
        *(uint2v*)(ep + off) = pk;
      }
    }
  }

  unsigned short* dst = qkvf + (size_t)mat * XTSZ + ((size_t)(c * 8 + h) << 12);
#pragma unroll
  for (int it = 0; it < 8; ++it) {
    int p = it * 64 + lane;
    int row = p >> 3, c16 = p & 7;
    short8 val = *(const short8*)(ep + ((row * 128 + c16 * 16) ^ ((row & 7) << 4)));
    *(short8*)(dst + row * 64 + c16 * 8) = val;
  }
}

// ---------------------------------------------------------------------------
// attn3: one wave per (chunk, head); verified body (R5).
__global__ __launch_bounds__(64, 3)
void attn3_kernel(const unsigned short* __restrict__ qkvf,
                  const float* __restrict__ masks,
                  const float* __restrict__ relk, const float* __restrict__ relv,
                  unsigned short* __restrict__ xo)
{
  __shared__ char ldsbuf[16384];
  char* regA = ldsbuf;            // Q tile, later V tile
  char* regB = ldsbuf + 8192;     // K tile, later P tile, later O tile
  const int lane = threadIdx.x;
  const int l15 = lane & 15, lg = lane >> 4;
  const int bid = blockIdx.x;
  const int c = bid >> 3, h = bid & 7;
  const int b = c >> 7, t0 = (c & 127) * 64;
  const size_t base = (size_t)(c * 8 + h) << 12;
  const unsigned short* qp = qkvf + base;
  const unsigned short* kp = qkvf + XTSZ + base;
  const unsigned short* vp = qkvf + 2 * XTSZ + base;

  float cmv = masks[(size_t)b * Tn + t0 + lane];
  unsigned long long nzb = __ballot(cmv != 0.0f);
  unsigned long long kpm = (nzb == 0ull) ? 0ull : __ballot(cmv == 0.0f);

  const f32x4 fzero = {0.f, 0.f, 0.f, 0.f};

  // ---- copy Q -> regA, K -> regB (swizzled; inverse of stream-out) ----
#pragma unroll
  for (int it = 0; it < 8; ++it) {
    int p = it * 64 + lane;
    int row = p >> 3, c16 = p & 7;
    int off = (row * 128 + c16 * 16) ^ ((row & 7) << 4);
    *(short8*)(regA + off) = *(const short8*)(qp + row * 64 + c16 * 8);
    *(short8*)(regB + off) = *(const short8*)(kp + row * 64 + c16 * 8);
  }

  // ---- S = Q K^T ----
  f32x4 sacc[4][4];
#pragma unroll
  for (int mi = 0; mi < 4; ++mi)
#pragma unroll
    for (int ni = 0; ni < 4; ++ni) sacc[mi][ni] = fzero;
#pragma unroll
  for (int kk = 0; kk < 2; ++kk) {
    short8 aq[4], bkf[4];
#pragma unroll
    for (int mi = 0; mi < 4; ++mi) {
      int t = mi * 16 + l15;
      int off = (t * 128 + (kk * 32 + lg * 8) * 2) ^ ((t & 7) << 4);
      aq[mi]  = *(const short8*)(regA + off);
      bkf[mi] = *(const short8*)(regB + off);
    }
#pragma unroll
    for (int ni = 0; ni < 4; ++ni)
#pragma unroll
      for (int mi = 0; mi < 4; ++mi)
        sacc[mi][ni] = __builtin_amdgcn_mfma_f32_16x16x32_bf16(aq[mi], bkf[ni], sacc[mi][ni], 0, 0, 0);
  }

  // ---- qrel[r] = sum_hd Q[qt=lane][hd] * rel_k[r][hd] ----
  float qr0 = 0, qr1 = 0, qr2 = 0, qr3 = 0, qr4 = 0;
#pragma unroll
  for (int g = 0; g < 8; ++g) {
    short8 q8 = *(const short8*)(regA + ((lane * 128 + g * 16) ^ ((lane & 7) << 4)));
#pragma unroll
    for (int j = 0; j < 8; ++j) {
      float qf = bf2f((unsigned short)q8[j]);
      qr0 += qf * relk[0 * 64 + g * 8 + j];
      qr1 += qf * relk[1 * 64 + g * 8 + j];
      qr2 += qf * relk[2 * 64 + g * 8 + j];
      qr3 += qf * relk[3 * 64 + g * 8 + j];
      qr4 += qf * relk[4 * 64 + g * 8 + j];
    }
  }

  // ---- copy V -> regA (Q dead after qrel) ----
#pragma unroll
  for (int it = 0; it < 8; ++it) {
    int p = it * 64 + lane;
    int row = p >> 3, c16 = p & 7;
    int off = (row * 128 + c16 * 16) ^ ((row & 7) << 4);
    *(short8*)(regA + off) = *(const short8*)(vp + row * 64 + c16 * 8);
  }

  // ---- softmax; P -> regB [qt][kt] (K dead) ----
  const float scale = 0.125f;
#pragma unroll
  for (int mi = 0; mi < 4; ++mi)
#pragma unroll
    for (int rr = 0; rr < 4; ++rr) {
      int qt = mi * 16 + lg * 4 + rr;
      float q0 = __shfl(qr0, qt), q1 = __shfl(qr1, qt), q2 = __shfl(qr2, qt),
            q3 = __shfl(qr3, qt), q4 = __shfl(qr4, qt);
      float sv[4];
#pragma unroll
      for (int ni = 0; ni < 4; ++ni) {
        int kt = ni * 16 + l15;
        int dd = kt - qt;
        float a2 = (dd <= -2) ? q0 : (dd == -1) ? q1 : (dd == 0) ? q2 : (dd == 1) ? q3 : q4;
        float s = (sacc[mi][ni][rr] + a2) * scale;
        if ((kpm >> kt) & 1ull) s = -1e30f;
        sv[ni] = s;
      }
      float m = fmaxf(fmaxf(sv[0], sv[1]), fmaxf(sv[2], sv[3]));
#pragma unroll
      for (int xm = 1; xm < 16; xm <<= 1) m = fmaxf(m, __shfl_xor(m, xm));
      float ssum = 0.f;
#pragma unroll
      for (int ni = 0; ni < 4; ++ni) { sv[ni] = __expf(sv[ni] - m); ssum += sv[ni]; }
#pragma unroll
      for (int xm = 1; xm < 16; xm <<= 1) ssum += __shfl_xor(ssum, xm);
      float inv = 1.0f / ssum;
#pragma unroll
      for (int ni = 0; ni < 4; ++ni) {
        int kt = ni * 16 + l15;
        int off = (qt * 128 + kt * 2) ^ ((qt & 7) << 4);
        *(unsigned short*)(regB + off) = f2bf(sv[ni] * inv);
      }
    }

  // ---- psum[qt=lane][r]: 5 class sums of P row ----
  float ps0 = 0, ps1 = 0, ps2 = 0, ps3 = 0, tot = 0;
#pragma unroll
  for (int g = 0; g < 8; ++g) {
    short8 p8 = *(const short8*)(regB + ((lane * 128 + g * 16) ^ ((lane & 7) << 4)));
#pragma unroll
    for (int j = 0; j < 8; ++j) {
      int kt = g * 8 + j;
      float p = bf2f((unsigned short)p8[j]);
      int dd = kt - lane;
      tot += p;
      ps0 += (dd <= -2) ? p : 0.f;
      ps1  = (dd == -1) ? p : ps1;
      ps2  = (dd ==  0) ? p : ps2;
      ps3  = (dd ==  1) ? p : ps3;
    }
  }
  float ps4 = tot - ps0 - ps1 - ps2 - ps3;

  // ---- O^T = V * P^T ----
  f32x4 oacc[4][4];
#pragma unroll
  for (int mi = 0; mi < 4; ++mi)
#pragma unroll
    for (int ni = 0; ni < 4; ++ni) oacc[mi][ni] = fzero;
#pragma unroll
  for (int kk = 0; kk < 2; ++kk) {
    short8 av[4], bp[4];
#pragma unroll
    for (int mi = 0; mi < 4; ++mi) {
      int row = mi * 16 + l15;
      int off = (row * 128 + (kk * 32 + lg * 8) * 2) ^ ((row & 7) << 4);
      av[mi] = *(const short8*)(regA + off);
      bp[mi] = *(const short8*)(regB + off);
    }
#pragma unroll
    for (int ni = 0; ni < 4; ++ni)
#pragma unroll
      for (int mi = 0; mi < 4; ++mi)
        oacc[mi][ni] = __builtin_amdgcn_mfma_f32_16x16x32_bf16(av[mi], bp[ni], oacc[mi][ni], 0, 0, 0);
  }

  // ---- O epilogue: +w2 (psum x rel_v); O -> regB [t][hd] ----
  float psh0[4], psh1[4], psh2[4], psh3[4], psh4[4];
#pragma unroll
  for (int ni = 0; ni < 4; ++ni) {
    int qt2 = ni * 16 + l15;
    psh0[ni] = __shfl(ps0, qt2); psh1[ni] = __shfl(ps1, qt2); psh2[ni] = __shfl(ps2, qt2);
    psh3[ni] = __shfl(ps3, qt2); psh4[ni] = __shfl(ps4, qt2);
  }
#pragma unroll
  for (int mi = 0; mi < 4; ++mi) {
    float rv_[4][5];
#pragma unroll
    for (int rr = 0; rr < 4; ++rr) {
      int hd = mi * 16 + lg * 4 + rr;
#pragma unroll
      for (int r = 0; r < 5; ++r) rv_[rr][r] = relv[r * 64 + hd];
    }
#pragma unroll
    for (int ni = 0; ni < 4; ++ni) {
      unsigned short u[4];
#pragma unroll
      for (int rr = 0; rr < 4; ++rr) {
        float w2 = psh0[ni] * rv_[rr][0] + psh1[ni] * rv_[rr][1] + psh2[ni] * rv_[rr][2]
                 + psh3[ni] * rv_[rr][3] + psh4[ni] * rv_[rr][4];
        u[rr] = f2bf(oacc[mi][ni][rr] + w2);
      }
      uint2v pk; pk[0] = u[0] | ((unsigned int)u[1] << 16);
      pk[1] = u[2] | ((unsigned int)u[3] << 16);
      int t = ni * 16 + l15;
      int off = (t * 128 + (mi * 16 + lg * 4) * 2) ^ ((t & 7) << 4);
      *(uint2v*)(regB + off) = pk;
    }
  }

  // ---- stream O tile to xo[t_g][512] ----
#pragma unroll
  for (int it = 0; it < 8; ++it) {
    int p = it * 64 + lane;
    int row = p >> 3, c16 = p & 7;
    short8 val = *(const short8*)(regB + ((row * 128 + c16 * 16) ^ ((row & 7) << 4)));
    *(short8*)(xo + (size_t)(c * 64 + row) * Dm + h * 64 + c16 * 8) = val;
  }
}

// ---------------------------------------------------------------------------
// outgemm: out[b][o][t] = (sum_d xo[t_g][d] * Wo[o][d] + bo[o]) * mask[b][t]
__global__ __launch_bounds__(256, 2)
void outgemm_kernel(const unsigned short* __restrict__ xo,
                    const unsigned short* __restrict__ wo,
                    const float* __restrict__ masks, const float* __restrict__ bo,
                    float* __restrict__ out)
{
  __shared__ char lA[16384], lB[16384];
  const int tid = threadIdx.x;
  const int lane = tid & 63, w = tid >> 6;
  const int wm = w >> 1, wn = w & 1;
  const int l15 = lane & 15, lg = lane >> 4;
  const int bidx = blockIdx.x;
  const int n0 = (bidx & 3) * 128, m0 = (bidx >> 2) * 128;

  f32x4 acc[4][4];
  const f32x4 fzero = {0.f, 0.f, 0.f, 0.f};
#pragma unroll
  for (int mi = 0; mi < 4; ++mi)
#pragma unroll
    for (int ni = 0; ni < 4; ++ni) acc[mi][ni] = fzero;

  for (int k0 = 0; k0 < 512; k0 += 64) {
#pragma unroll
    for (int it = 0; it < 4; ++it) {
      int slot = it * 256 + w * 64 + lane;
      int row = slot >> 3, c16 = slot & 7;
      int gcol = k0 + ((c16 ^ (row & 7)) * 8);
      gload16(lA + it * 4096 + w * 1024, xo + (size_t)(m0 + row) * Dm + gcol);
      gload16(lB + it * 4096 + w * 1024, wo + (size_t)(n0 + row) * Dm + gcol);
    }
    __syncthreads();
#pragma unroll
    for (int kk = 0; kk < 2; ++kk) {
      short8 af[4], bf_[4];
#pragma unroll
      for (int mi = 0; mi < 4; ++mi) {
        int m = wm * 64 + mi * 16 + l15;
        af[mi] = *(const short8*)(lA + ((m * 128 + (kk * 32 + lg * 8) * 2) ^ ((m & 7) << 4)));
      }
#pragma unroll
      for (int ni = 0; ni < 4; ++ni) {
        int n = wn * 64 + ni * 16 + l15;
        bf_[ni] = *(const short8*)(lB + ((n * 128 + (kk * 32 + lg * 8) * 2) ^ ((n & 7) << 4)));
      }
#pragma unroll
      for (int ni = 0; ni < 4; ++ni)
#pragma unroll
        for (int mi = 0; mi < 4; ++mi)
          acc[mi][ni] = __builtin_amdgcn_mfma_f32_16x16x32_bf16(af[mi], bf_[ni], acc[mi][ni], 0, 0, 0);
    }
    __syncthreads();
  }

#pragma unroll
  for (int mi = 0; mi < 4; ++mi) {
    int tg = m0 + wm * 64 + mi * 16 + lg * 4;
    int b = tg >> 13, t = tg & (Tn - 1);
    f32x4 mv = *(const f32x4*)(masks + (size_t)b * Tn + t);
#pragma unroll
    for (int ni = 0; ni < 4; ++ni) {
      int o = n0 + wn * 64 + ni * 16 + l15;
      float bia = bo[o];
      f32x4 r;
#pragma unroll
      for (int rr = 0; rr < 4; ++rr) r[rr] = (acc[mi][ni][rr] + bia) * mv[rr];
      *(f32x4*)(out + ((size_t)b * Dm + o) * Tn + t) = r;
    }
  }
}

// ===========================================================================
// Fallback: round-2 fused2 path (ws too small for split pipeline)
// ===========================================================================
__global__ __launch_bounds__(512, 2)
void fused2_kernel(const unsigned short* __restrict__ xt,
                   const float* __restrict__ masks,
                   const unsigned short* __restrict__ wbf,
                   const float* __restrict__ bq, const float* __restrict__ bk,
                   const float* __restrict__ bv, const float* __restrict__ bo,
                   const float* __restrict__ relk, const float* __restrict__ relv,
                   float* __restrict__ out)
{
  extern __shared__ char lds[];
  const int tid  = threadIdx.x;
  const int lane = tid & 63;
  const int w    = tid >> 6;
  const int l15  = lane & 15;
  const int lg   = lane >> 4;
  const int c    = blockIdx.x;
  const int b    = c >> 7;
  const int t0   = (c & (Gn - 1)) * NC;

  char* regA = lds + w * 16384;
  char* regB = regA + 8192;

  float cmv = masks[(size_t)b * Tn + t0 + lane];
  unsigned long long nzb = __ballot(cmv != 0.0f);
  unsigned long long kpm = (nzb == 0ull) ? 0ull : __ballot(cmv == 0.0f);

  const f32x4 fzero = {0.f, 0.f, 0.f, 0.f};
  const int aoff = l15 * 32 + lg * 8;
  const unsigned short* xq = xt + ((size_t)c << 15);
  const unsigned short* xk = xq + XTSZ;
  const unsigned short* xv = xq + 2 * XTSZ;

  auto project = [&](const unsigned short* __restrict__ xb,
                     const unsigned short* __restrict__ wb, f32x4 (&acc)[4][4]) {
#pragma unroll
    for (int mi = 0; mi < 4; ++mi)
#pragma unroll
      for (int ni = 0; ni < 4; ++ni) acc[mi][ni] = fzero;
#pragma unroll
    for (int kk = 0; kk < 16; ++kk) {
      short8 af[4], bf_[4];
#pragma unroll
      for (int mi = 0; mi < 4; ++mi)
        af[mi] = *(const short8*)(xb + kk * 2048 + mi * 512 + aoff);
#pragma unroll
      for (int ni = 0; ni < 4; ++ni)
        bf_[ni] = *(const short8*)(wb + kk * 2048 + ni * 512 + aoff);
#pragma unroll
      for (int ni = 0; ni < 4; ++ni)
#pragma unroll
        for (int mi = 0; mi < 4; ++mi)
          acc[mi][ni] = __builtin_amdgcn_mfma_f32_16x16x32_bf16(af[mi], bf_[ni],
                                                                acc[mi][ni], 0, 0, 0);
    }
  };

  f32x4 acc[4][4];

  project(xq, wbf + 0 * WSZ + w * 32768, acc);
#pragma unroll
  for (int ni = 0; ni < 4; ++ni) {
    float bia = bq[64 * w + ni * 16 + l15];
    int hd = ni * 16 + l15;
#pragma unroll
    for (int mi = 0; mi < 4; ++mi)
#pragma unroll
      for (int rr = 0; rr < 4; ++rr) {
        int t = mi * 16 + lg * 4 + rr;
        int off = (t * 128 + hd * 2) ^ ((t & 7) << 4);
        *(unsigned short*)(regA + off) = f2bf(acc[mi][ni][rr] + bia);
      }
  }

  project(xk, wbf + 1 * WSZ + w * 32768, acc);
#pragma unroll
  for (int ni = 0; ni < 4; ++ni) {
    float bia = bk[64 * w + ni * 16 + l15];
    int hd = ni * 16 + l15;
#pragma unroll
    for (int mi = 0; mi < 4; ++mi)
#pragma unroll
      for (int rr = 0; rr < 4; ++rr) {
        int t = mi * 16 + lg * 4 + rr;
        int off = (t * 128 + hd * 2) ^ ((t & 7) << 4);
        *(unsigned short*)(regB + off) = f2bf(acc[mi][ni][rr] + bia);
      }
  }

  f32x4 sacc[4][4];
#pragma unroll
  for (int mi = 0; mi < 4; ++mi)
#pragma unroll
    for (int ni = 0; ni < 4; ++ni) sacc[mi][ni] = fzero;
#pragma unroll
  for (int kk = 0; kk < 2; ++kk) {
    short8 aq[4], bkf[4];
#pragma unroll
    for (int mi = 0; mi < 4; ++mi) {
      int t = mi * 16 + l15;
      int off = (t * 128 + (kk * 32 + lg * 8) * 2) ^ ((t & 7) << 4);
      aq[mi]  = *(const short8*)(regA + off);
      bkf[mi] = *(const short8*)(regB + off);
    }
#pragma unroll
    for (int ni = 0; ni < 4; ++ni)
#pragma unroll
      for (int mi = 0; mi < 4; ++mi)
        sacc[mi][ni] = __builtin_amdgcn_mfma_f32_16x16x32_bf16(aq[mi], bkf[ni],
                                                               sacc[mi][ni], 0, 0, 0);
  }

  float qr0 = 0, qr1 = 0, qr2 = 0, qr3 = 0, qr4 = 0;
#pragma unroll
  for (int g = 0; g < 8; ++g) {
    short8 q8 = *(const short8*)(regA + ((lane * 128 + g * 16) ^ ((lane & 7) << 4)));
#pragma unroll
    for (int j = 0; j < 8; ++j) {
      float qf = bf2f((unsigned short)q8[j]);
      qr0 += qf * relk[0 * 64 + g * 8 + j];
      qr1 += qf * relk[1 * 64 + g * 8 + j];
      qr2 += qf * relk[2 * 64 + g * 8 + j];
      qr3 += qf * relk[3 * 64 + g * 8 + j];
      qr4 += qf * relk[4 * 64 + g * 8 + j];
    }
  }

  const float scale = 0.125f;
#pragma unroll
  for (int mi = 0; mi < 4; ++mi)
#pragma unroll
    for (int rr = 0; rr < 4; ++rr) {
      int qt = mi * 16 + lg * 4 + rr;
      float q0 = __shfl(qr0, qt), q1 = __shfl(qr1, qt), q2 = __shfl(qr2, qt),
            q3 = __shfl(qr3, qt), q4 = __shfl(qr4, qt);
      float sv[4];
#pragma unroll
      for (int ni = 0; ni < 4; ++ni) {
        int kt = ni * 16 + l15;
        int dd = kt - qt;
        float a2 = (dd <= -2) ? q0 : (dd == -1) ? q1 : (dd == 0) ? q2 : (dd == 1) ? q3 : q4;
        float s = (sacc[mi][ni][rr] + a2) * scale;
        if ((kpm >> kt) & 1ull) s = -1e30f;
        sv[ni] = s;
      }
      float m = fmaxf(fmaxf(sv[0], sv[1]), fmaxf(sv[2], sv[3]));
#pragma unroll
      for (int xm = 1; xm < 16; xm <<= 1) m = fmaxf(m, __shfl_xor(m, xm));
      float ssum = 0.f;
#pragma unroll
      for (int ni = 0; ni < 4; ++ni) { sv[ni] = __expf(sv[ni] - m); ssum += sv[ni]; }
#pragma unroll
      for (int xm = 1; xm < 16; xm <<= 1) ssum += __shfl_xor(ssum, xm);
      float inv = 1.0f / ssum;
#pragma unroll
      for (int ni = 0; ni < 4; ++ni) {
        int kt = ni * 16 + l15;
        int off = (qt * 128 + kt * 2) ^ ((qt & 7) << 4);
        *(unsigned short*)(regB + off) = f2bf(sv[ni] * inv);
      }
    }

  float ps0 = 0, ps1 = 0, ps2 = 0, ps3 = 0, tot = 0;
#pragma unroll
  for (int g = 0; g < 8; ++g) {
    short8 p8 = *(const short8*)(regB + ((lane * 128 + g * 16) ^ ((lane & 7) << 4)));
#pragma unroll
    for (int j = 0; j < 8; ++j) {
      int kt = g * 8 + j;
      float p = bf2f((unsigned short)p8[j]);
      int dd = kt - lane;
      tot += p;
      ps0 += (dd <= -2) ? p : 0.f;
      ps1  = (dd == -1) ? p : ps1;
      ps2  = (dd ==  0) ? p : ps2;
      ps3  = (dd ==  1) ? p : ps3;
    }
  }
  float ps4 = tot - ps0 - ps1 - ps2 - ps3;

  project(xv, wbf + 2 * WSZ + w * 32768, acc);
#pragma unroll
  for (int ni = 0; ni < 4; ++ni) {
    float bia = bv[64 * w + ni * 16 + l15];
    int hd = ni * 16 + l15;
#pragma unroll
    for (int mi = 0; mi < 4; ++mi) {
      unsigned int lo = (unsigned int)f2bf(acc[mi][ni][0] + bia) |
                        ((unsigned int)f2bf(acc[mi][ni][1] + bia) << 16);
      unsigned int hi = (unsigned int)f2bf(acc[mi][ni][2] + bia) |
                        ((unsigned int)f2bf(acc[mi][ni][3] + bia) << 16);
      uint2v pk; pk[0] = lo; pk[1] = hi;
      int off = (hd * 128 + (mi * 16 + lg * 4) * 2) ^ ((hd & 7) << 4);
      *(uint2v*)(regA + off) = pk;
    }
  }

  f32x4 oacc[4][4];
#pragma unroll
  for (int mi = 0; mi < 4; ++mi)
#pragma unroll
    for (int ni = 0; ni < 4; ++ni) oacc[mi][ni] = fzero;
#pragma unroll
  for (int kk = 0; kk < 2; ++kk) {
    short8 av[4], bp[4];
#pragma unroll
    for (int mi = 0; mi < 4; ++mi) {
      int row = mi * 16 + l15;
      int off = (row * 128 + (kk * 32 + lg * 8) * 2) ^ ((row & 7) << 4);
      av[mi] = *(const short8*)(regA + off);
      bp[mi] = *(const short8*)(regB + off);
    }
#pragma unroll
    for (int ni = 0; ni < 4; ++ni)
#pragma unroll
      for (int mi = 0; mi < 4; ++mi)
        oacc[mi][ni] = __builtin_amdgcn_mfma_f32_16x16x32_bf16(av[mi], bp[ni],
                                                               oacc[mi][ni], 0, 0, 0);
  }

  float psh0[4], psh1[4], psh2[4], psh3[4], psh4[4];
#pragma unroll
  for (int ni = 0; ni < 4; ++ni) {
    int qt2 = ni * 16 + l15;
    psh0[ni] = __shfl(ps0, qt2); psh1[ni] = __shfl(ps1, qt2); psh2[ni] = __shfl(ps2, qt2);
    psh3[ni] = __shfl(ps3, qt2); psh4[ni] = __shfl(ps4, qt2);
  }
  uint2v xop[4][4];
#pragma unroll
  for (int mi = 0; mi < 4; ++mi) {
    float rv_[4][5];
#pragma unroll
    for (int rr = 0; rr < 4; ++rr) {
      int hd = mi * 16 + lg * 4 + rr;
#pragma unroll
      for (int r = 0; r < 5; ++r) rv_[rr][r] = relv[r * 64 + hd];
    }
#pragma unroll
    for (int ni = 0; ni < 4; ++ni) {
      unsigned short u[4];
#pragma unroll
      for (int rr = 0; rr < 4; ++rr) {
        float w2 = psh0[ni] * rv_[rr][0] + psh1[ni] * rv_[rr][1] + psh2[ni] * rv_[rr][2]
                 + psh3[ni] * rv_[rr][3] + psh4[ni] * rv_[rr][4];
        u[rr] = f2bf(oacc[mi][ni][rr] + w2);
      }
      uint2v pk; pk[0] = u[0] | ((unsigned int)u[1] << 16);
      pk[1] = u[2] | ((unsigned int)u[3] << 16);
      xop[mi][ni] = pk;
    }
  }

  __syncthreads();
  char* xobuf = lds;
#pragma unroll
  for (int ni = 0; ni < 4; ++ni) {
    int t = ni * 16 + l15;
#pragma unroll
    for (int mi = 0; mi < 4; ++mi) {
      int d = 64 * w + mi * 16 + lg * 4;
      int off = (t * 1024 + d * 2) ^ ((t & 15) << 4);
      *(uint2v*)(xobuf + off) = xop[mi][ni];
    }
  }
  __syncthreads();

  f32x4 cacc[4][4];
#pragma unroll
  for (int mi = 0; mi < 4; ++mi)
#pragma unroll
    for (int ni = 0; ni < 4; ++ni) cacc[mi][ni] = fzero;
  const unsigned short* wob = wbf + 3 * WSZ + w * 32768;
#pragma unroll
  for (int kk = 0; kk < 16; ++kk) {
    short8 ax[4], bw[4];
#pragma unroll
    for (int mi = 0; mi < 4; ++mi) {
      int t = mi * 16 + l15;
      int off = (t * 1024 + (kk * 32 + lg * 8) * 2) ^ ((t & 15) << 4);
      ax[mi] = *(const short8*)(xobuf + off);
    }
#pragma unroll
    for (int ni = 0; ni < 4; ++ni)
      bw[ni] = *(const short8*)(wob + kk * 2048 + ni * 512 + l15 * 32 + lg * 8);
#pragma unroll
    for (int ni = 0; ni < 4; ++ni)
#pragma unroll
      for (int mi = 0; mi < 4; ++mi)
        cacc[mi][ni] = __builtin_amdgcn_mfma_f32_16x16x32_bf16(ax[mi], bw[ni],
                                                               cacc[mi][ni], 0, 0, 0);
  }
#pragma unroll
  for (int mi = 0; mi < 4; ++mi) {
    int tl = mi * 16 + lg * 4;
    f32x4 mv = *(const f32x4*)(masks + (size_t)b * Tn + t0 + tl);
#pragma unroll
    for (int ni = 0; ni < 4; ++ni) {
      int o = 64 * w + ni * 16 + l15;
      float bia = bo[o];
      f32x4 r;
#pragma unroll
      for (int rr = 0; rr < 4; ++rr) r[rr] = (cacc[mi][ni][rr] + bia) * mv[rr];
      *(f32x4*)(out + ((size_t)b * Dm + o) * Tn + t0 + tl) = r;
    }
  }
}

// ---------------------------------------------------------------------------
extern "C" void kernel_launch(void* const* d_in, const int* in_sizes, int n_in,
                              void* d_out, int out_size, void* d_ws, size_t ws_size,
                              hipStream_t stream) {
  (void)in_sizes; (void)n_in; (void)out_size;
  const float* q  = (const float*)d_in[0];
  const float* k  = (const float*)d_in[1];
  const float* v  = (const float*)d_in[2];
  const float* ms = (const float*)d_in[3];
  const float* Wq = (const float*)d_in[4];
  const float* bq = (const float*)d_in[5];
  const float* Wk = (const float*)d_in[6];
  const float* bk = (const float*)d_in[7];
  const float* Wv = (const float*)d_in[8];
  const float* bv = (const float*)d_in[9];
  const float* Wo = (const float*)d_in[10];
  const float* bo = (const float*)d_in[11];
  const float* rk = (const float*)d_in[12];
  const float* rv = (const float*)d_in[13];
  float* out = (float*)d_out;

  const size_t needNew = ((size_t)4 * WSZ + 4 * XTSZ) * 2;   // ~136 MB

  if (ws_size >= needNew) {
    unsigned short* wt3   = (unsigned short*)d_ws;     // tiled Wq|Wk|Wv
    unsigned short* worow = wt3 + 3 * WSZ;             // row-major Wo
    unsigned short* qkvf  = worow + WSZ;               // Qf|Kf|Vf
    unsigned short* xo    = qkvf + 3 * XTSZ;           // attention output
    wcvt3_tiled<<<dim3(768), dim3(256), 0, stream>>>(Wq, Wk, Wv, wt3);
    wcvt_row1<<<dim3(256), dim3(256), 0, stream>>>(Wo, worow);
    qkvproj3_kernel<<<dim3(1536), dim3(512), 0, stream>>>(q, k, v, wt3,
                                                          bq, bk, bv, qkvf);
    attn3_kernel<<<dim3(4096), dim3(64), 0, stream>>>(qkvf, ms, rk, rv, xo);
    outgemm_kernel<<<dim3(1024), dim3(256), 0, stream>>>(xo, worow, ms, bo, out);
  } else {
    unsigned short* wbf = (unsigned short*)d_ws;
    unsigned short* xt = wbf + 4 * WSZ;
    wcvt_tiled<<<dim3(1024), dim3(256), 0, stream>>>(Wq, Wk, Wv, Wo, wbf);
    xpose_kernel<<<dim3(12288), dim3(256), 0, stream>>>(q, k, v, xt);
    hipFuncSetAttribute((const void*)fused2_kernel,
                        hipFuncAttributeMaxDynamicSharedMemorySize, 131072);
    fused2_kernel<<<dim3(BG), dim3(512), 131072, stream>>>(xt, ms, wbf,
                                                           bq, bk, bv, bo, rk, rv, out);
  }
}